// Round 4
// baseline (636.530 us; speedup 1.0000x reference)
//
#include <hip/hip_runtime.h>

// LoG = GaussianBlur(3x3,sigma=1,REFLECT_101) -> Laplacian(9x9,REFLECT_101) -> +1 -> clip[0,255]
// x: [32,512,512,3] f32 NHWC.
//
// Interior algebra (verified in R3): Sg = S9*g3, Dg = D9*g3 (11-tap composites);
//   hS = horz(Sg,x), hD = horz(Dg,x);  out[r] = sum_k Sg[k]*hD[r-5+k] + Dg[k]*hS[r-5+k] + 1.
// Borders (first/last 5 rows/cols) don't collapse; exact two-stage folded weights
// FTAB (R3-verified) over the 10 nearest physical rows/cols, constexpr-baked.
//
// Structure: 32x32 tile, 8192 blocks, 2 phases, 1 barrier.
//   P1: hS/hD rows G0..G1 (<=42) from global via float4 window loads -> LDS.
//   P2: vertical 11-tap streamed in k, 4-row register blocking, clamp, store.

#define NT    384
#define HIMG  512
#define ROWF  1536
#define NQ    24          // float4 quads per tile row (96 floats)
#define LSTR  96          // LDS row stride (floats)
#define MAXG  42

// 11-tap composite kernels (double-folded; same constants passed R3)
__device__ constexpr float SGc[11] = {
    0.27406861900052384f, 2.6444117140031430f, 11.562892047006810f,
    30.192548952004191f, 52.163039333992666f, 62.326078667985332f,
    52.163039333992666f, 30.192548952004191f, 11.562892047006810f,
    2.6444117140031430f, 0.27406861900052384f};
__device__ constexpr float DGc[11] = {
    0.27406861900052384f, 1.5481372380010477f, 3.1777941429984285f,
    1.8074510479958093f, -3.4518627619989523f, -6.7111765719937139f,
    -3.4518627619989523f, 1.8074510479958093f, 3.1777941429984285f,
    1.5481372380010477f, 0.27406861900052384f};

// folded two-stage border weights w[p][m], p=0..4 (dist from edge), m=0..9 (phys idx)
struct FT_t { float s[5][10]; float d[5][10]; };
constexpr int reflc(int i) { int a = i < 0 ? -i : i; return a >= 512 ? 1022 - a : a; }
constexpr FT_t mkft() {
    FT_t t{};
    const double F9s[9] = {1,8,28,56,70,56,28,8,1};
    const double F9d[9] = {1,4,4,-4,-10,-4,4,4,1};
    const double A = 0.27406861900052384, B = 0.45186276199895232;
    const double g3[3] = {A, B, A};
    for (int p = 0; p < 5; ++p)
        for (int m = 0; m < 10; ++m) {
            double as = 0.0, ad = 0.0;
            for (int j = 0; j < 9; ++j) {
                int b = reflc(p - 4 + j);
                for (int i = 0; i < 3; ++i)
                    if (reflc(b - 1 + i) == m) { as += F9s[j] * g3[i]; ad += F9d[j] * g3[i]; }
            }
            t.s[p][m] = (float)as; t.d[p][m] = (float)ad;
        }
    return t;
}
__device__ constexpr FT_t FTAB = mkft();

__global__ __launch_bounds__(NT, 6)
void log_tile(const float* __restrict__ x, float* __restrict__ out) {
    __shared__ __align__(16) float sh[2 * MAXG * LSTR];   // 32256 B
    float* const hS = sh;
    float* const hD = sh + MAXG * LSTR;

    const int tid  = threadIdx.x;
    const int bx   = blockIdx.x, by = blockIdx.y;
    const int col0 = bx * 32, r0 = by * 32;
    const int G0   = max(0, r0 - 5);
    const int G1   = min(HIMG - 1, r0 + 36);
    const int nG   = G1 - G0 + 1;                         // 37 or 42
    const float* xn = x   + (size_t)blockIdx.z * (HIMG * ROWF);
    float* on       = out + (size_t)blockIdx.z * (HIMG * ROWF);

    // ---- P1: horizontal 11-tap composites -> LDS (column-stationary) ----
    const int q    = tid % NQ;
    const int rsub = tid / NQ;           // 0..15, rows rsub, rsub+16, rsub+32
    const int f0   = 4 * q;
    const bool bl  = (bx == 0  && q < 4);
    const bool br  = (bx == 15 && q >= 20);

    for (int r = rsub; r < nG; r += 16) {
        const float* xr = xn + (size_t)(G0 + r) * ROWF;
        float vsv[4], vdv[4];
        if (!bl && !br) {
            // window floats [f0-16, f0+20): 9 aligned float4 loads
            float w[36];
            const float4* wp = (const float4*)(xr + col0 * 3 + f0 - 16);
            #pragma unroll
            for (int u = 0; u < 9; ++u) {
                float4 v = wp[u];
                w[4*u+0] = v.x; w[4*u+1] = v.y; w[4*u+2] = v.z; w[4*u+3] = v.w;
            }
            #pragma unroll
            for (int j = 0; j < 4; ++j) {
                float c = w[j + 16];
                float s = SGc[5] * c, d = DGc[5] * c;
                #pragma unroll
                for (int k = 0; k < 5; ++k) {            // symmetric pairs
                    float p = w[j + 1 + 3*k] + w[j + 31 - 3*k];
                    s = fmaf(SGc[k], p, s);
                    d = fmaf(DGc[k], p, d);
                }
                vsv[j] = s; vdv[j] = d;
            }
        } else if (bl) {
            float w[32];                                  // x floats 0..31
            const float4* wp = (const float4*)xr;
            #pragma unroll
            for (int u = 0; u < 8; ++u) {
                float4 v = wp[u];
                w[4*u+0] = v.x; w[4*u+1] = v.y; w[4*u+2] = v.z; w[4*u+3] = v.w;
            }
            #pragma unroll
            for (int j = 0; j < 4; ++j) {
                const int f = f0 + j, p = f / 3, ch = f - 3 * p;
                float s = 0.f, d = 0.f;
                if (p <= 4) {
                    #pragma unroll
                    for (int m = 0; m < 10; ++m) {
                        float xv = w[3*m + ch];
                        s = fmaf(FTAB.s[p][m], xv, s);
                        d = fmaf(FTAB.d[p][m], xv, d);
                    }
                } else {                                  // f == 15 (pc == 5)
                    #pragma unroll
                    for (int k = 0; k < 11; ++k) {
                        float xv = w[3*k];
                        s = fmaf(SGc[k], xv, s);
                        d = fmaf(DGc[k], xv, d);
                    }
                }
                vsv[j] = s; vdv[j] = d;
            }
        } else {
            float w[32];                                  // x floats 1504..1535
            const float4* wp = (const float4*)(xr + 1504);
            #pragma unroll
            for (int u = 0; u < 8; ++u) {
                float4 v = wp[u];
                w[4*u+0] = v.x; w[4*u+1] = v.y; w[4*u+2] = v.z; w[4*u+3] = v.w;
            }
            #pragma unroll
            for (int j = 0; j < 4; ++j) {
                const int f = f0 + j, p = f / 3, ch = f - 3 * p;
                const int pc = 480 + p;
                float s = 0.f, d = 0.f;
                if (pc >= 507) {
                    const int rr = 511 - pc;
                    #pragma unroll
                    for (int m = 0; m < 10; ++m) {
                        float xv = w[29 - 3*m + ch];      // x col 3*(511-m)+ch
                        s = fmaf(FTAB.s[rr][m], xv, s);
                        d = fmaf(FTAB.d[rr][m], xv, d);
                    }
                } else {                                  // f == 80 (pc == 506)
                    #pragma unroll
                    for (int k = 0; k < 11; ++k) {
                        float xv = w[1 + 3*k];            // fc-15+3k - 1504
                        s = fmaf(SGc[k], xv, s);
                        d = fmaf(DGc[k], xv, d);
                    }
                }
                vsv[j] = s; vdv[j] = d;
            }
        }
        *(float4*)&hS[r * LSTR + f0] = make_float4(vsv[0], vsv[1], vsv[2], vsv[3]);
        *(float4*)&hD[r * LSTR + f0] = make_float4(vdv[0], vdv[1], vdv[2], vdv[3]);
    }
    __syncthreads();

    // ---- P2: vertical 11-tap combine, 4-row register blocking, streamed k ----
    if (tid < 192) {
        const int q2 = tid % NQ, rg = tid / NQ;           // rg 0..7
        const int lr0   = 4 * rg;
        const int rbase = r0 + lr0;
        const int cb    = 4 * q2;
        float* const op0 = on + (size_t)rbase * ROWF + (size_t)(col0 * 3 + cb);

        if (rbase >= 5 && rbase + 3 <= 506) {
            float4 acc[4];
            #pragma unroll
            for (int i = 0; i < 4; ++i) acc[i] = make_float4(1.f, 1.f, 1.f, 1.f);
            const int pb = rbase - 5 - G0;
            #pragma unroll
            for (int k = 0; k < 14; ++k) {
                const float4 d = *(const float4*)&hD[(pb + k) * LSTR + cb];
                const float4 s = *(const float4*)&hS[(pb + k) * LSTR + cb];
                #pragma unroll
                for (int i = 0; i < 4; ++i) {
                    const int kt = k - i;
                    if (kt >= 0 && kt <= 10) {
                        float4 a = acc[i];
                        a.x = fmaf(SGc[kt], d.x, a.x); a.y = fmaf(SGc[kt], d.y, a.y);
                        a.z = fmaf(SGc[kt], d.z, a.z); a.w = fmaf(SGc[kt], d.w, a.w);
                        a.x = fmaf(DGc[kt], s.x, a.x); a.y = fmaf(DGc[kt], s.y, a.y);
                        a.z = fmaf(DGc[kt], s.z, a.z); a.w = fmaf(DGc[kt], s.w, a.w);
                        acc[i] = a;
                    }
                }
            }
            #pragma unroll
            for (int i = 0; i < 4; ++i) {
                float4 o = acc[i];
                o.x = fminf(fmaxf(o.x, 0.f), 255.f);
                o.y = fminf(fmaxf(o.y, 0.f), 255.f);
                o.z = fminf(fmaxf(o.z, 0.f), 255.f);
                o.w = fminf(fmaxf(o.w, 0.f), 255.f);
                *(float4*)(op0 + (size_t)i * ROWF) = o;
            }
        } else {
            // mixed border/interior rows: per-row paths (only by==0 / by==15 tiles)
            #pragma unroll
            for (int i = 0; i < 4; ++i) {
                const int r = rbase + i;
                float4 a = make_float4(1.f, 1.f, 1.f, 1.f);
                if (r < 5) {
                    #pragma unroll
                    for (int m = 0; m < 10; ++m) {
                        const float ws = FTAB.s[r][m], wd = FTAB.d[r][m];
                        const float4 d = *(const float4*)&hD[m * LSTR + cb];
                        const float4 s = *(const float4*)&hS[m * LSTR + cb];
                        a.x = fmaf(ws, d.x, a.x); a.y = fmaf(ws, d.y, a.y);
                        a.z = fmaf(ws, d.z, a.z); a.w = fmaf(ws, d.w, a.w);
                        a.x = fmaf(wd, s.x, a.x); a.y = fmaf(wd, s.y, a.y);
                        a.z = fmaf(wd, s.z, a.z); a.w = fmaf(wd, s.w, a.w);
                    }
                } else if (r > 506) {
                    const int rr = 511 - r;
                    #pragma unroll
                    for (int m = 0; m < 10; ++m) {
                        const float ws = FTAB.s[rr][m], wd = FTAB.d[rr][m];
                        const int pi = 36 - m;            // phys row 511-m, G0=475
                        const float4 d = *(const float4*)&hD[pi * LSTR + cb];
                        const float4 s = *(const float4*)&hS[pi * LSTR + cb];
                        a.x = fmaf(ws, d.x, a.x); a.y = fmaf(ws, d.y, a.y);
                        a.z = fmaf(ws, d.z, a.z); a.w = fmaf(ws, d.w, a.w);
                        a.x = fmaf(wd, s.x, a.x); a.y = fmaf(wd, s.y, a.y);
                        a.z = fmaf(wd, s.z, a.z); a.w = fmaf(wd, s.w, a.w);
                    }
                } else {
                    const int pb = r - 5 - G0;
                    #pragma unroll
                    for (int k = 0; k < 11; ++k) {
                        const float4 d = *(const float4*)&hD[(pb + k) * LSTR + cb];
                        const float4 s = *(const float4*)&hS[(pb + k) * LSTR + cb];
                        a.x = fmaf(SGc[k], d.x, a.x); a.y = fmaf(SGc[k], d.y, a.y);
                        a.z = fmaf(SGc[k], d.z, a.z); a.w = fmaf(SGc[k], d.w, a.w);
                        a.x = fmaf(DGc[k], s.x, a.x); a.y = fmaf(DGc[k], s.y, a.y);
                        a.z = fmaf(DGc[k], s.z, a.z); a.w = fmaf(DGc[k], s.w, a.w);
                    }
                }
                a.x = fminf(fmaxf(a.x, 0.f), 255.f);
                a.y = fminf(fmaxf(a.y, 0.f), 255.f);
                a.z = fminf(fmaxf(a.z, 0.f), 255.f);
                a.w = fminf(fmaxf(a.w, 0.f), 255.f);
                *(float4*)(op0 + (size_t)i * ROWF) = a;
            }
        }
    }
}

extern "C" void kernel_launch(void* const* d_in, const int* in_sizes, int n_in,
                              void* d_out, int out_size, void* d_ws, size_t ws_size,
                              hipStream_t stream) {
    const float* x = (const float*)d_in[0];
    float* outp = (float*)d_out;
    const int nimg = in_sizes[0] / (HIMG * ROWF);
    dim3 grid(16, 16, nimg);
    log_tile<<<grid, dim3(NT, 1, 1), 0, stream>>>(x, outp);
}

// Round 5
// 472.149 us; speedup vs baseline: 1.3482x; 1.3482x over previous
//
#include <hip/hip_runtime.h>

// LoG = GaussianBlur(3x3,sigma=1,REFLECT_101) -> Laplacian(9x9,REFLECT_101) -> +1 -> clip[0,255]
// x: [32,512,512,3] f32 NHWC.
//
// Interior algebra (R3/R4-verified): Sg = S9*g3, Dg = D9*g3 (11-tap composites);
//   hS = horz(Sg,x), hD = horz(Dg,x);  out[r] = sum_k Sg[k]*hD[r-5+k] + Dg[k]*hS[r-5+k] + 1.
// Borders (first/last 5 rows/cols): exact two-stage folded weights FTAB over the
// 10 nearest physical rows/cols (constexpr-baked, R3/R4-verified).
//
// R5 vs R4: 256 threads + launch_bounds(256,4) (VGPR cap 128 -- R4's (384,6) cap 85
// forced w[36] into scratch: VGPR 40, WRITE 487 MB, 522 us), unroll(disable) on the
// P1 item loop to block cross-iteration pipelining, LDS 32256 B -> 5 blocks/CU.

#define NT    256
#define HIMG  512
#define ROWF  1536
#define NQ    24          // float4 quads per tile row (96 floats)
#define LSTR  96          // LDS row stride (floats)
#define MAXG  42

__device__ constexpr float SGc[11] = {
    0.27406861900052384f, 2.6444117140031430f, 11.562892047006810f,
    30.192548952004191f, 52.163039333992666f, 62.326078667985332f,
    52.163039333992666f, 30.192548952004191f, 11.562892047006810f,
    2.6444117140031430f, 0.27406861900052384f};
__device__ constexpr float DGc[11] = {
    0.27406861900052384f, 1.5481372380010477f, 3.1777941429984285f,
    1.8074510479958093f, -3.4518627619989523f, -6.7111765719937139f,
    -3.4518627619989523f, 1.8074510479958093f, 3.1777941429984285f,
    1.5481372380010477f, 0.27406861900052384f};

struct FT_t { float s[5][10]; float d[5][10]; };
constexpr int reflc(int i) { int a = i < 0 ? -i : i; return a >= 512 ? 1022 - a : a; }
constexpr FT_t mkft() {
    FT_t t{};
    const double F9s[9] = {1,8,28,56,70,56,28,8,1};
    const double F9d[9] = {1,4,4,-4,-10,-4,4,4,1};
    const double A = 0.27406861900052384, B = 0.45186276199895232;
    const double g3[3] = {A, B, A};
    for (int p = 0; p < 5; ++p)
        for (int m = 0; m < 10; ++m) {
            double as = 0.0, ad = 0.0;
            for (int j = 0; j < 9; ++j) {
                int b = reflc(p - 4 + j);
                for (int i = 0; i < 3; ++i)
                    if (reflc(b - 1 + i) == m) { as += F9s[j] * g3[i]; ad += F9d[j] * g3[i]; }
            }
            t.s[p][m] = (float)as; t.d[p][m] = (float)ad;
        }
    return t;
}
__device__ constexpr FT_t FTAB = mkft();

__global__ __launch_bounds__(NT, 4)
void log_tile(const float* __restrict__ x, float* __restrict__ out) {
    __shared__ __align__(16) float sh[2 * MAXG * LSTR];   // 32256 B => 5 blocks/CU
    float* const hS = sh;
    float* const hD = sh + MAXG * LSTR;

    const int tid  = threadIdx.x;
    const int bx   = blockIdx.x, by = blockIdx.y;
    const int col0 = bx * 32, r0 = by * 32;
    const int G0   = max(0, r0 - 5);
    const int G1   = min(HIMG - 1, r0 + 36);
    const int nG   = G1 - G0 + 1;                         // 37 or 42
    const float* xn = x   + (size_t)blockIdx.z * (HIMG * ROWF);
    float* on       = out + (size_t)blockIdx.z * (HIMG * ROWF);

    // ---- P1: horizontal 11-tap composites -> LDS (item = (row, quad)) ----
    const int nitems = nG * NQ;
    #pragma clang loop unroll(disable)
    for (int it = tid; it < nitems; it += NT) {
        const int r  = it / NQ;
        const int q  = it - NQ * r;
        const int f0 = 4 * q;
        const float* xr = xn + (size_t)(G0 + r) * ROWF;
        float vsv[4], vdv[4];
        const bool bl = (bx == 0  && q < 4);
        const bool br = (bx == 15 && q >= 20);
        if (!bl && !br) {
            // window floats [f0-16, f0+20): 9 aligned float4 loads
            float w[36];
            const float4* wp = (const float4*)(xr + col0 * 3 + f0 - 16);
            #pragma unroll
            for (int u = 0; u < 9; ++u) {
                float4 v = wp[u];
                w[4*u+0] = v.x; w[4*u+1] = v.y; w[4*u+2] = v.z; w[4*u+3] = v.w;
            }
            #pragma unroll
            for (int j = 0; j < 4; ++j) {
                float c = w[j + 16];
                float s = SGc[5] * c, d = DGc[5] * c;
                #pragma unroll
                for (int k = 0; k < 5; ++k) {            // symmetric pairs
                    float p = w[j + 1 + 3*k] + w[j + 31 - 3*k];
                    s = fmaf(SGc[k], p, s);
                    d = fmaf(DGc[k], p, d);
                }
                vsv[j] = s; vdv[j] = d;
            }
        } else if (bl) {
            float w[32];                                  // x floats 0..31
            const float4* wp = (const float4*)xr;
            #pragma unroll
            for (int u = 0; u < 8; ++u) {
                float4 v = wp[u];
                w[4*u+0] = v.x; w[4*u+1] = v.y; w[4*u+2] = v.z; w[4*u+3] = v.w;
            }
            #pragma unroll
            for (int j = 0; j < 4; ++j) {
                const int f = f0 + j, p = f / 3, ch = f - 3 * p;
                float s = 0.f, d = 0.f;
                if (p <= 4) {
                    #pragma unroll
                    for (int m = 0; m < 10; ++m) {
                        float xv = w[3*m + ch];
                        s = fmaf(FTAB.s[p][m], xv, s);
                        d = fmaf(FTAB.d[p][m], xv, d);
                    }
                } else {                                  // f == 15 (pc == 5)
                    #pragma unroll
                    for (int k = 0; k < 11; ++k) {
                        float xv = w[3*k];
                        s = fmaf(SGc[k], xv, s);
                        d = fmaf(DGc[k], xv, d);
                    }
                }
                vsv[j] = s; vdv[j] = d;
            }
        } else {
            float w[32];                                  // x floats 1504..1535
            const float4* wp = (const float4*)(xr + 1504);
            #pragma unroll
            for (int u = 0; u < 8; ++u) {
                float4 v = wp[u];
                w[4*u+0] = v.x; w[4*u+1] = v.y; w[4*u+2] = v.z; w[4*u+3] = v.w;
            }
            #pragma unroll
            for (int j = 0; j < 4; ++j) {
                const int f = f0 + j, p = f / 3, ch = f - 3 * p;
                const int pc = 480 + p;
                float s = 0.f, d = 0.f;
                if (pc >= 507) {
                    const int rr = 511 - pc;
                    #pragma unroll
                    for (int m = 0; m < 10; ++m) {
                        float xv = w[29 - 3*m + ch];      // x col 3*(511-m)+ch
                        s = fmaf(FTAB.s[rr][m], xv, s);
                        d = fmaf(FTAB.d[rr][m], xv, d);
                    }
                } else {                                  // f == 80 (pc == 506)
                    #pragma unroll
                    for (int k = 0; k < 11; ++k) {
                        float xv = w[1 + 3*k];
                        s = fmaf(SGc[k], xv, s);
                        d = fmaf(DGc[k], xv, d);
                    }
                }
                vsv[j] = s; vdv[j] = d;
            }
        }
        *(float4*)&hS[r * LSTR + f0] = make_float4(vsv[0], vsv[1], vsv[2], vsv[3]);
        *(float4*)&hD[r * LSTR + f0] = make_float4(vdv[0], vdv[1], vdv[2], vdv[3]);
    }
    __syncthreads();

    // ---- P2: vertical 11-tap combine, 4-row register blocking, streamed k ----
    if (tid < 192) {
        const int q2 = tid % NQ, rg = tid / NQ;           // rg 0..7
        const int lr0   = 4 * rg;
        const int rbase = r0 + lr0;
        const int cb    = 4 * q2;
        float* const op0 = on + (size_t)rbase * ROWF + (size_t)(col0 * 3 + cb);

        if (rbase >= 5 && rbase + 3 <= 506) {
            float4 acc[4];
            #pragma unroll
            for (int i = 0; i < 4; ++i) acc[i] = make_float4(1.f, 1.f, 1.f, 1.f);
            const int pb = rbase - 5 - G0;
            #pragma unroll
            for (int k = 0; k < 14; ++k) {
                const float4 d = *(const float4*)&hD[(pb + k) * LSTR + cb];
                const float4 s = *(const float4*)&hS[(pb + k) * LSTR + cb];
                #pragma unroll
                for (int i = 0; i < 4; ++i) {
                    const int kt = k - i;
                    if (kt >= 0 && kt <= 10) {
                        float4 a = acc[i];
                        a.x = fmaf(SGc[kt], d.x, a.x); a.y = fmaf(SGc[kt], d.y, a.y);
                        a.z = fmaf(SGc[kt], d.z, a.z); a.w = fmaf(SGc[kt], d.w, a.w);
                        a.x = fmaf(DGc[kt], s.x, a.x); a.y = fmaf(DGc[kt], s.y, a.y);
                        a.z = fmaf(DGc[kt], s.z, a.z); a.w = fmaf(DGc[kt], s.w, a.w);
                        acc[i] = a;
                    }
                }
            }
            #pragma unroll
            for (int i = 0; i < 4; ++i) {
                float4 o = acc[i];
                o.x = fminf(fmaxf(o.x, 0.f), 255.f);
                o.y = fminf(fmaxf(o.y, 0.f), 255.f);
                o.z = fminf(fmaxf(o.z, 0.f), 255.f);
                o.w = fminf(fmaxf(o.w, 0.f), 255.f);
                *(float4*)(op0 + (size_t)i * ROWF) = o;
            }
        } else {
            // mixed border/interior rows (only by==0 / by==15 tiles)
            #pragma unroll
            for (int i = 0; i < 4; ++i) {
                const int r = rbase + i;
                float4 a = make_float4(1.f, 1.f, 1.f, 1.f);
                if (r < 5) {
                    #pragma unroll
                    for (int m = 0; m < 10; ++m) {
                        const float ws = FTAB.s[r][m], wd = FTAB.d[r][m];
                        const float4 d = *(const float4*)&hD[m * LSTR + cb];
                        const float4 s = *(const float4*)&hS[m * LSTR + cb];
                        a.x = fmaf(ws, d.x, a.x); a.y = fmaf(ws, d.y, a.y);
                        a.z = fmaf(ws, d.z, a.z); a.w = fmaf(ws, d.w, a.w);
                        a.x = fmaf(wd, s.x, a.x); a.y = fmaf(wd, s.y, a.y);
                        a.z = fmaf(wd, s.z, a.z); a.w = fmaf(wd, s.w, a.w);
                    }
                } else if (r > 506) {
                    const int rr = 511 - r;
                    #pragma unroll
                    for (int m = 0; m < 10; ++m) {
                        const float ws = FTAB.s[rr][m], wd = FTAB.d[rr][m];
                        const int pi = 36 - m;            // phys row 511-m (G0=475)
                        const float4 d = *(const float4*)&hD[pi * LSTR + cb];
                        const float4 s = *(const float4*)&hS[pi * LSTR + cb];
                        a.x = fmaf(ws, d.x, a.x); a.y = fmaf(ws, d.y, a.y);
                        a.z = fmaf(ws, d.z, a.z); a.w = fmaf(ws, d.w, a.w);
                        a.x = fmaf(wd, s.x, a.x); a.y = fmaf(wd, s.y, a.y);
                        a.z = fmaf(wd, s.z, a.z); a.w = fmaf(wd, s.w, a.w);
                    }
                } else {
                    const int pb = r - 5 - G0;
                    #pragma unroll
                    for (int k = 0; k < 11; ++k) {
                        const float4 d = *(const float4*)&hD[(pb + k) * LSTR + cb];
                        const float4 s = *(const float4*)&hS[(pb + k) * LSTR + cb];
                        a.x = fmaf(SGc[k], d.x, a.x); a.y = fmaf(SGc[k], d.y, a.y);
                        a.z = fmaf(SGc[k], d.z, a.z); a.w = fmaf(SGc[k], d.w, a.w);
                        a.x = fmaf(DGc[k], s.x, a.x); a.y = fmaf(DGc[k], s.y, a.y);
                        a.z = fmaf(DGc[k], s.z, a.z); a.w = fmaf(DGc[k], s.w, a.w);
                    }
                }
                a.x = fminf(fmaxf(a.x, 0.f), 255.f);
                a.y = fminf(fmaxf(a.y, 0.f), 255.f);
                a.z = fminf(fmaxf(a.z, 0.f), 255.f);
                a.w = fminf(fmaxf(a.w, 0.f), 255.f);
                *(float4*)(op0 + (size_t)i * ROWF) = a;
            }
        }
    }
}

extern "C" void kernel_launch(void* const* d_in, const int* in_sizes, int n_in,
                              void* d_out, int out_size, void* d_ws, size_t ws_size,
                              hipStream_t stream) {
    const float* x = (const float*)d_in[0];
    float* outp = (float*)d_out;
    const int nimg = in_sizes[0] / (HIMG * ROWF);
    dim3 grid(16, 16, nimg);
    log_tile<<<grid, dim3(NT, 1, 1), 0, stream>>>(x, outp);
}

// Round 6
// 416.485 us; speedup vs baseline: 1.5283x; 1.1336x over previous
//
#include <hip/hip_runtime.h>

// LoG = GaussianBlur(3x3,sigma=1,REFLECT_101) -> Laplacian(9x9,REFLECT_101) -> +1 -> clip[0,255]
// x: [32,512,512,3] f32 NHWC.
//
// Algebra (R3/R4/R5-verified): Sg = S9*g3, Dg = D9*g3 (11-tap composites);
//   hS = horz(Sg,x), hD = horz(Dg,x);  out[r] = sum_k Sg[k]*hD[r-5+k] + Dg[k]*hS[r-5+k] + 1.
// Borders (first/last 5 rows/cols): exact two-stage folded weights FTAB (verified).
//
// R6 vs R5: P1's 9 global window-loads per item (uncoalesced, latency-serialized;
// R5: VALU 10%, occ 13%, WRITE +56MB) replaced by coalesced float4 staging of raw
// x into LDS (P1a) + LDS window reads (P1b). P2 unchanged (verified). 2 barriers.

#define NT    256
#define HIMG  512
#define ROWF  1536
#define NQ    24          // float4 quads per hS/hD row (96 floats)
#define LSTR  96          // hS/hD row stride (floats)
#define XSTR  128         // xt row stride (floats) = 32 quads
#define MAXG  42

__device__ constexpr float SGc[11] = {
    0.27406861900052384f, 2.6444117140031430f, 11.562892047006810f,
    30.192548952004191f, 52.163039333992666f, 62.326078667985332f,
    52.163039333992666f, 30.192548952004191f, 11.562892047006810f,
    2.6444117140031430f, 0.27406861900052384f};
__device__ constexpr float DGc[11] = {
    0.27406861900052384f, 1.5481372380010477f, 3.1777941429984285f,
    1.8074510479958093f, -3.4518627619989523f, -6.7111765719937139f,
    -3.4518627619989523f, 1.8074510479958093f, 3.1777941429984285f,
    1.5481372380010477f, 0.27406861900052384f};

struct FT_t { float s[5][10]; float d[5][10]; };
constexpr int reflc(int i) { int a = i < 0 ? -i : i; return a >= 512 ? 1022 - a : a; }
constexpr FT_t mkft() {
    FT_t t{};
    const double F9s[9] = {1,8,28,56,70,56,28,8,1};
    const double F9d[9] = {1,4,4,-4,-10,-4,4,4,1};
    const double A = 0.27406861900052384, B = 0.45186276199895232;
    const double g3[3] = {A, B, A};
    for (int p = 0; p < 5; ++p)
        for (int m = 0; m < 10; ++m) {
            double as = 0.0, ad = 0.0;
            for (int j = 0; j < 9; ++j) {
                int b = reflc(p - 4 + j);
                for (int i = 0; i < 3; ++i)
                    if (reflc(b - 1 + i) == m) { as += F9s[j] * g3[i]; ad += F9d[j] * g3[i]; }
            }
            t.s[p][m] = (float)as; t.d[p][m] = (float)ad;
        }
    return t;
}
__device__ constexpr FT_t FTAB = mkft();

__global__ __launch_bounds__(NT, 4)
void log_tile(const float* __restrict__ x, float* __restrict__ out) {
    __shared__ __align__(16) float hS[MAXG * LSTR];   // 16128 B
    __shared__ __align__(16) float hD[MAXG * LSTR];   // 16128 B
    __shared__ __align__(16) float xt[MAXG * XSTR];   // 21504 B  => 53760 total, 3 blk/CU

    const int tid  = threadIdx.x;
    const int bx   = blockIdx.x, by = blockIdx.y;
    const int col0 = bx * 32, r0 = by * 32;
    const int G0   = max(0, r0 - 5);
    const int G1   = min(HIMG - 1, r0 + 36);
    const int nG   = G1 - G0 + 1;                     // 37 or 42
    const float* xn = x   + (size_t)blockIdx.z * (HIMG * ROWF);
    float* on       = out + (size_t)blockIdx.z * (HIMG * ROWF);

    // ---- P1a: coalesced raw-x staging -> xt ----
    // xt row r holds x floats [col0*3-16, col0*3+112) of image row G0+r; global quad
    // index clamped to [0,383] at bx==0/15 -- clamped slots are never read (borders
    // use FTAB over physical cols which live at xt[16..47] / xt[80..111]).
    {
        const int base_q = 24 * bx - 4;
        const int nIt = nG * 32;
        #pragma unroll
        for (int i = 0; i < 6; ++i) {
            const int it = tid + 256 * i;
            if (it < nIt) {
                const int r  = it >> 5;
                const int qq = it & 31;
                const int gq = min(max(base_q + qq, 0), 383);
                const float4 v = *(const float4*)(xn + (size_t)(G0 + r) * ROWF + 4 * gq);
                *(float4*)&xt[r * XSTR + 4 * qq] = v;
            }
        }
    }
    __syncthreads();

    // ---- P1b: horizontal 11-tap composites from xt windows -> hS, hD ----
    {
        const int nIt = nG * NQ;
        #pragma unroll
        for (int i = 0; i < 4; ++i) {
            const int it = tid + 256 * i;
            if (it < nIt) {
                const int r  = it / NQ;
                const int q  = it - NQ * r;
                const int f0 = 4 * q;
                const float* xr = &xt[r * XSTR];
                float vsv[4], vdv[4];
                const bool bl = (bx == 0  && q < 4);
                const bool br = (bx == 15 && q >= 20);
                if (!bl && !br) {
                    // window = x floats [col0*3+f0-16, +20) = xt[f0 .. f0+36)
                    float w[36];
                    const float4* wp = (const float4*)(xr + f0);
                    #pragma unroll
                    for (int u = 0; u < 9; ++u) {
                        float4 v = wp[u];
                        w[4*u+0] = v.x; w[4*u+1] = v.y; w[4*u+2] = v.z; w[4*u+3] = v.w;
                    }
                    #pragma unroll
                    for (int j = 0; j < 4; ++j) {
                        float c = w[j + 16];
                        float s = SGc[5] * c, d = DGc[5] * c;
                        #pragma unroll
                        for (int k = 0; k < 5; ++k) {        // symmetric pairs
                            float p = w[j + 1 + 3*k] + w[j + 31 - 3*k];
                            s = fmaf(SGc[k], p, s);
                            d = fmaf(DGc[k], p, d);
                        }
                        vsv[j] = s; vdv[j] = d;
                    }
                } else if (bl) {
                    // x floats 0..31 = xt[16..47]
                    float w[32];
                    const float4* wp = (const float4*)(xr + 16);
                    #pragma unroll
                    for (int u = 0; u < 8; ++u) {
                        float4 v = wp[u];
                        w[4*u+0] = v.x; w[4*u+1] = v.y; w[4*u+2] = v.z; w[4*u+3] = v.w;
                    }
                    #pragma unroll
                    for (int j = 0; j < 4; ++j) {
                        const int f = f0 + j, p = f / 3, ch = f - 3 * p;
                        float s = 0.f, d = 0.f;
                        if (p <= 4) {
                            #pragma unroll
                            for (int m = 0; m < 10; ++m) {
                                float xv = w[3*m + ch];
                                s = fmaf(FTAB.s[p][m], xv, s);
                                d = fmaf(FTAB.d[p][m], xv, d);
                            }
                        } else {                              // f == 15 (pc == 5)
                            #pragma unroll
                            for (int k = 0; k < 11; ++k) {
                                float xv = w[3*k];
                                s = fmaf(SGc[k], xv, s);
                                d = fmaf(DGc[k], xv, d);
                            }
                        }
                        vsv[j] = s; vdv[j] = d;
                    }
                } else {
                    // x floats 1504..1535 = xt[80..111]  (window start = 1424)
                    float w[32];
                    const float4* wp = (const float4*)(xr + 80);
                    #pragma unroll
                    for (int u = 0; u < 8; ++u) {
                        float4 v = wp[u];
                        w[4*u+0] = v.x; w[4*u+1] = v.y; w[4*u+2] = v.z; w[4*u+3] = v.w;
                    }
                    #pragma unroll
                    for (int j = 0; j < 4; ++j) {
                        const int f = f0 + j, p = f / 3, ch = f - 3 * p;
                        const int pc = 480 + p;
                        float s = 0.f, d = 0.f;
                        if (pc >= 507) {
                            const int rr = 511 - pc;
                            #pragma unroll
                            for (int m = 0; m < 10; ++m) {
                                float xv = w[29 - 3*m + ch];  // x col 3*(511-m)+ch
                                s = fmaf(FTAB.s[rr][m], xv, s);
                                d = fmaf(FTAB.d[rr][m], xv, d);
                            }
                        } else {                              // f == 80 (pc == 506)
                            #pragma unroll
                            for (int k = 0; k < 11; ++k) {
                                float xv = w[1 + 3*k];
                                s = fmaf(SGc[k], xv, s);
                                d = fmaf(DGc[k], xv, d);
                            }
                        }
                        vsv[j] = s; vdv[j] = d;
                    }
                }
                *(float4*)&hS[r * LSTR + f0] = make_float4(vsv[0], vsv[1], vsv[2], vsv[3]);
                *(float4*)&hD[r * LSTR + f0] = make_float4(vdv[0], vdv[1], vdv[2], vdv[3]);
            }
        }
    }
    __syncthreads();

    // ---- P2: vertical 11-tap combine, 4-row register blocking (R5-verified) ----
    if (tid < 192) {
        const int q2 = tid % NQ, rg = tid / NQ;           // rg 0..7
        const int lr0   = 4 * rg;
        const int rbase = r0 + lr0;
        const int cb    = 4 * q2;
        float* const op0 = on + (size_t)rbase * ROWF + (size_t)(col0 * 3 + cb);

        if (rbase >= 5 && rbase + 3 <= 506) {
            float4 acc[4];
            #pragma unroll
            for (int i = 0; i < 4; ++i) acc[i] = make_float4(1.f, 1.f, 1.f, 1.f);
            const int pb = rbase - 5 - G0;
            #pragma unroll
            for (int k = 0; k < 14; ++k) {
                const float4 d = *(const float4*)&hD[(pb + k) * LSTR + cb];
                const float4 s = *(const float4*)&hS[(pb + k) * LSTR + cb];
                #pragma unroll
                for (int i = 0; i < 4; ++i) {
                    const int kt = k - i;
                    if (kt >= 0 && kt <= 10) {
                        float4 a = acc[i];
                        a.x = fmaf(SGc[kt], d.x, a.x); a.y = fmaf(SGc[kt], d.y, a.y);
                        a.z = fmaf(SGc[kt], d.z, a.z); a.w = fmaf(SGc[kt], d.w, a.w);
                        a.x = fmaf(DGc[kt], s.x, a.x); a.y = fmaf(DGc[kt], s.y, a.y);
                        a.z = fmaf(DGc[kt], s.z, a.z); a.w = fmaf(DGc[kt], s.w, a.w);
                        acc[i] = a;
                    }
                }
            }
            #pragma unroll
            for (int i = 0; i < 4; ++i) {
                float4 o = acc[i];
                o.x = fminf(fmaxf(o.x, 0.f), 255.f);
                o.y = fminf(fmaxf(o.y, 0.f), 255.f);
                o.z = fminf(fmaxf(o.z, 0.f), 255.f);
                o.w = fminf(fmaxf(o.w, 0.f), 255.f);
                *(float4*)(op0 + (size_t)i * ROWF) = o;
            }
        } else {
            // mixed border/interior rows (only by==0 / by==15 tiles)
            #pragma unroll
            for (int i = 0; i < 4; ++i) {
                const int r = rbase + i;
                float4 a = make_float4(1.f, 1.f, 1.f, 1.f);
                if (r < 5) {
                    #pragma unroll
                    for (int m = 0; m < 10; ++m) {
                        const float ws = FTAB.s[r][m], wd = FTAB.d[r][m];
                        const float4 d = *(const float4*)&hD[m * LSTR + cb];
                        const float4 s = *(const float4*)&hS[m * LSTR + cb];
                        a.x = fmaf(ws, d.x, a.x); a.y = fmaf(ws, d.y, a.y);
                        a.z = fmaf(ws, d.z, a.z); a.w = fmaf(ws, d.w, a.w);
                        a.x = fmaf(wd, s.x, a.x); a.y = fmaf(wd, s.y, a.y);
                        a.z = fmaf(wd, s.z, a.z); a.w = fmaf(wd, s.w, a.w);
                    }
                } else if (r > 506) {
                    const int rr = 511 - r;
                    #pragma unroll
                    for (int m = 0; m < 10; ++m) {
                        const float ws = FTAB.s[rr][m], wd = FTAB.d[rr][m];
                        const int pi = 36 - m;            // phys row 511-m (G0=475)
                        const float4 d = *(const float4*)&hD[pi * LSTR + cb];
                        const float4 s = *(const float4*)&hS[pi * LSTR + cb];
                        a.x = fmaf(ws, d.x, a.x); a.y = fmaf(ws, d.y, a.y);
                        a.z = fmaf(ws, d.z, a.z); a.w = fmaf(ws, d.w, a.w);
                        a.x = fmaf(wd, s.x, a.x); a.y = fmaf(wd, s.y, a.y);
                        a.z = fmaf(wd, s.z, a.z); a.w = fmaf(wd, s.w, a.w);
                    }
                } else {
                    const int pb = r - 5 - G0;
                    #pragma unroll
                    for (int k = 0; k < 11; ++k) {
                        const float4 d = *(const float4*)&hD[(pb + k) * LSTR + cb];
                        const float4 s = *(const float4*)&hS[(pb + k) * LSTR + cb];
                        a.x = fmaf(SGc[k], d.x, a.x); a.y = fmaf(SGc[k], d.y, a.y);
                        a.z = fmaf(SGc[k], d.z, a.z); a.w = fmaf(SGc[k], d.w, a.w);
                        a.x = fmaf(DGc[k], s.x, a.x); a.y = fmaf(DGc[k], s.y, a.y);
                        a.z = fmaf(DGc[k], s.z, a.z); a.w = fmaf(DGc[k], s.w, a.w);
                    }
                }
                a.x = fminf(fmaxf(a.x, 0.f), 255.f);
                a.y = fminf(fmaxf(a.y, 0.f), 255.f);
                a.z = fminf(fmaxf(a.z, 0.f), 255.f);
                a.w = fminf(fmaxf(a.w, 0.f), 255.f);
                *(float4*)(op0 + (size_t)i * ROWF) = a;
            }
        }
    }
}

extern "C" void kernel_launch(void* const* d_in, const int* in_sizes, int n_in,
                              void* d_out, int out_size, void* d_ws, size_t ws_size,
                              hipStream_t stream) {
    const float* x = (const float*)d_in[0];
    float* outp = (float*)d_out;
    const int nimg = in_sizes[0] / (HIMG * ROWF);
    dim3 grid(16, 16, nimg);
    log_tile<<<grid, dim3(NT, 1, 1), 0, stream>>>(x, outp);
}